// Round 12
// baseline (1435.732 us; speedup 1.0000x reference)
//
#include <hip/hip_runtime.h>
#include <math.h>

#define NB 256
#define LM 16
#define HID 512
#define H4 2048
#define D2 1024
#define D5 5120
#define NPAIR0 3840   // 256*15
#define INC_CAP 512   // max incremental rows (2 per batch)

typedef __attribute__((ext_vector_type(8))) short bf16x8;
typedef __attribute__((ext_vector_type(4))) float f32x4;

__device__ __forceinline__ float sigm(float x) { return 1.0f / (1.0f + expf(-x)); }

__device__ __forceinline__ unsigned short bf16_rne(float f) {
    union { float f; unsigned u; } v; v.f = f;
    unsigned u = v.u;
    return (unsigned short)((u + 0x7fffu + ((u >> 16) & 1u)) >> 16);
}
__device__ __forceinline__ float bf16_tof(unsigned short h) {
    union { unsigned u; float f; } v; v.u = ((unsigned)h) << 16;
    return v.f;
}

// async global->LDS, 16B per lane; dest = wave-uniform base + lane*16
__device__ __forceinline__ void gload16(const unsigned short* g, unsigned short* l) {
    __builtin_amdgcn_global_load_lds(
        (const __attribute__((address_space(1))) void*)(const void*)g,
        (__attribute__((address_space(3))) void*)(void*)l, 16, 0, 0);
}

// ---------------------------------------------------------------------------
// init: zero LSTM state, slot maps, uncompacted + length-compacted rowlists,
// logits = -1e30 (missing pairs stay masked). rcount must be pre-zeroed.
// Compacted count lives in rcount[15]; merges own rcount[0..14].
// ---------------------------------------------------------------------------
__global__ __launch_bounds__(256)
void init_kernel(const int* __restrict__ lens, float* ccur,
                 unsigned short* hc_hi, unsigned short* hc_lo,
                 int* pos, int* pair, int4* rowlist0, int4* rowlist_c,
                 int* rcount, float* logits)
{
    int b = blockIdx.x, tid = threadIdx.x;
    for (int u = tid; u < HID; u += 256) {
        ccur[(size_t)b * HID + u] = 0.f;
        ccur[((size_t)NB + b) * HID + u] = 0.f;
        hc_hi[(size_t)b * HID + u] = 0;
        hc_hi[((size_t)NB + b) * HID + u] = 0;
        hc_lo[(size_t)b * HID + u] = 0;
        hc_lo[((size_t)NB + b) * HID + u] = 0;
    }
    if (tid < 16) { pos[b * 16 + tid] = tid; pair[b * 16 + tid] = tid; logits[b * 16 + tid] = -1e30f; }
    if (tid < 15) rowlist0[b * 15 + tid] = make_int4(b, tid, tid + 1, tid | (tid << 16));
    __shared__ int sbase;
    int len = lens[b];
    if (tid == 0) sbase = atomicAdd(rcount + 15, len - 1);
    __syncthreads();
    if (tid < len - 1) rowlist_c[sbase + tid] = make_int4(b, tid, tid + 1, tid | (tid << 16));
}

// ---------------------------------------------------------------------------
__global__ __launch_bounds__(256)
void split_w(const float4* __restrict__ w, unsigned short* __restrict__ hi,
             unsigned short* __restrict__ lo, int n4)
{
    for (int i = blockIdx.x * 256 + threadIdx.x; i < n4; i += gridDim.x * 256) {
        float4 f = w[i];
        ushort4 h, l;
        h.x = bf16_rne(f.x); l.x = bf16_rne(f.x - bf16_tof(h.x));
        h.y = bf16_rne(f.y); l.y = bf16_rne(f.y - bf16_tof(h.y));
        h.z = bf16_rne(f.z); l.z = bf16_rne(f.z - bf16_tof(h.z));
        h.w = bf16_rne(f.w); l.w = bf16_rne(f.w - bf16_tof(h.w));
        ((ushort4*)hi)[i] = h;
        ((ushort4*)lo)[i] = l;
    }
}

// ---------------------------------------------------------------------------
__global__ __launch_bounds__(256)
void pack_lstm_w(const float* __restrict__ w_ih_f, const float* __restrict__ w_hh_f,
                 const float* __restrict__ w_ih_b, const float* __restrict__ w_hh_b,
                 unsigned short* __restrict__ wl_hi, unsigned short* __restrict__ wl_lo)
{
    const int total4 = 2 * H4 * 256;
    for (int i = blockIdx.x * 256 + threadIdx.x; i < total4; i += gridDim.x * 256) {
        int k4 = i & 255;
        int j = (i >> 8) & 2047;
        int dir = i >> 19;
        const float* wih = dir ? w_ih_b : w_ih_f;
        const float* whh = dir ? w_hh_b : w_hh_f;
        float4 f = (k4 < 128) ? *(const float4*)(wih + (size_t)j * HID + k4 * 4)
                              : *(const float4*)(whh + (size_t)j * HID + (k4 - 128) * 4);
        ushort4 h, l;
        h.x = bf16_rne(f.x); l.x = bf16_rne(f.x - bf16_tof(h.x));
        h.y = bf16_rne(f.y); l.y = bf16_rne(f.y - bf16_tof(h.y));
        h.z = bf16_rne(f.z); l.z = bf16_rne(f.z - bf16_tof(h.z));
        h.w = bf16_rne(f.w); l.w = bf16_rne(f.w - bf16_tof(h.w));
        ((ushort4*)wl_hi)[i] = h;
        ((ushort4*)wl_lo)[i] = l;
    }
}

// ---------------------------------------------------------------------------
// LSTM step GEMM: gload_lds staging, double-buffered LDS, swizzled.
// Split-K x2 + grouped 1D mapping (round-11 proven version).
// ---------------------------------------------------------------------------
__global__ __launch_bounds__(256)
void gemm_lstm_g(int t, const int* __restrict__ lens,
                 const unsigned short* __restrict__ x_hi, const unsigned short* __restrict__ x_lo,
                 const unsigned short* __restrict__ hc_hi, const unsigned short* __restrict__ hc_lo,
                 const unsigned short* __restrict__ wl_hi, const unsigned short* __restrict__ wl_lo,
                 float* __restrict__ gbuf)
{
    constexpr int SA = 64 * 32;        // shorts per A plane
    constexpr int SB = 128 * 32;       // shorts per B plane
    constexpr int BUF = 2 * SA + 2 * SB;

    const int bid = blockIdx.x;
    const int x8 = bid & 7, r = bid >> 3;
    const int sub = r & 3, gq = r >> 2;
    const int g = x8 + 8 * gq;         // 0..63
    const int row0 = sub * 64;
    const int col0 = (g & 15) * 128;
    const int zz = g >> 4;
    const int dir = zz & 1;
    const int kz = zz >> 1;
    const int kbeg = kz * 512, kend = kbeg + 512;
    float* gout = gbuf + (size_t)kz * 2 * NB * H4;

    const int tid = threadIdx.x, lane = tid & 63, w = tid >> 6;
    const int wm = w >> 1, wn = w & 1;

    __shared__ __align__(16) unsigned short smem[2 * BUF];

    const int sz8 = ((lane & 3) ^ ((lane >> 3) & 3)) * 8;  // swizzled source part
    const int b0 = row0 + w * 16 + (lane >> 2);
    const int len = lens[b0];
    const int trow = dir ? ((t < len) ? (len - 1 - t) : t) : t;
    const size_t xoff = ((size_t)(b0 * LM + trow)) * HID;
    const size_t hoff = ((size_t)(dir * NB + b0)) * HID;

    size_t colOff[2];
#pragma unroll
    for (int cs = 0; cs < 2; ++cs)
        colOff[cs] = ((size_t)(dir * H4 + col0 + (w + 4 * cs) * 16 + (lane >> 2))) * 1024;

    auto stage = [&](int d, int k) {
        unsigned short* sb = smem + d * BUF;
        const unsigned short* sh = (k < HID) ? (x_hi + xoff + k) : (hc_hi + hoff + (k - HID));
        gload16(sh + sz8, sb + w * 512);
        const unsigned short* sl = (k < HID) ? (x_lo + xoff + k) : (hc_lo + hoff + (k - HID));
        gload16(sl + sz8, sb + SA + w * 512);
#pragma unroll
        for (int j = 0; j < 4; ++j) {
            const int pl = j >> 1, cs = j & 1;
            const unsigned short* wb = pl ? wl_lo : wl_hi;
            gload16(wb + colOff[cs] + k + sz8, sb + 2 * SA + pl * SB + (w + 4 * cs) * 512);
        }
    };

    f32x4 acc[2][4];
#pragma unroll
    for (int i = 0; i < 2; ++i)
#pragma unroll
        for (int j = 0; j < 4; ++j) acc[i][j] = (f32x4){0.f, 0.f, 0.f, 0.f};

    const int rsw = ((lane >> 4) ^ ((lane >> 1) & 3)) * 8;   // swizzled read slot
    const int a_off = (wm * 32 + (lane & 15)) * 32 + rsw;
    const int b_off = 2 * SA + (wn * 64 + (lane & 15)) * 32 + rsw;

    stage(0, kbeg);
    __syncthreads();
    int cur = 0;
    for (int k0 = kbeg; k0 < kend; k0 += 32) {
        if (k0 + 32 < kend) stage(cur ^ 1, k0 + 32);
        const unsigned short* sb = smem + cur * BUF;
        bf16x8 ah[2], al[2];
#pragma unroll
        for (int fm = 0; fm < 2; ++fm) {
            ah[fm] = *(const bf16x8*)&sb[a_off + fm * 512];
            al[fm] = *(const bf16x8*)&sb[SA + a_off + fm * 512];
        }
#pragma unroll
        for (int fn = 0; fn < 4; ++fn) {
            bf16x8 bh = *(const bf16x8*)&sb[b_off + fn * 512];
            bf16x8 bl = *(const bf16x8*)&sb[SB + b_off + fn * 512];
#pragma unroll
            for (int fm = 0; fm < 2; ++fm) {
                acc[fm][fn] = __builtin_amdgcn_mfma_f32_16x16x32_bf16(ah[fm], bh, acc[fm][fn], 0, 0, 0);
                acc[fm][fn] = __builtin_amdgcn_mfma_f32_16x16x32_bf16(ah[fm], bl, acc[fm][fn], 0, 0, 0);
                acc[fm][fn] = __builtin_amdgcn_mfma_f32_16x16x32_bf16(al[fm], bh, acc[fm][fn], 0, 0, 0);
            }
        }
        __syncthreads();
        cur ^= 1;
    }

#pragma unroll
    for (int fm = 0; fm < 2; ++fm) {
        int rbase = row0 + wm * 32 + fm * 16 + (lane >> 4) * 4;
#pragma unroll
        for (int fn = 0; fn < 4; ++fn) {
            int c = col0 + wn * 64 + fn * 16 + (lane & 15);
#pragma unroll
            for (int q = 0; q < 4; ++q)
                gout[((size_t)(dir * NB + rbase + q)) * H4 + c] = acc[fm][fn][q];
        }
    }
}

// ---------------------------------------------------------------------------
__global__ __launch_bounds__(256)
void lstm_gate(int t, const int* __restrict__ lengths,
               const float* __restrict__ b_f, const float* __restrict__ b_b,
               const float* __restrict__ g_buf, float* __restrict__ ccur,
               unsigned short* __restrict__ hc_hi, unsigned short* __restrict__ hc_lo,
               unsigned short* __restrict__ h_hi, unsigned short* __restrict__ h_lo,
               float* __restrict__ c_seq)
{
    int b = blockIdx.x, dir = blockIdx.y, tid = threadIdx.x;
    const float* bias = dir ? b_b : b_f;
    int len = lengths[b];
    int pos = dir ? ((t < len) ? (len - 1 - t) : t) : t;
    const float* g0 = g_buf + ((size_t)(dir * NB + b)) * H4;
    const float* g1 = g0 + (size_t)2 * NB * H4;
    float* cc = ccur + ((size_t)(dir * NB + b)) * HID;
    unsigned short* hch = hc_hi + ((size_t)(dir * NB + b)) * HID;
    unsigned short* hcl = hc_lo + ((size_t)(dir * NB + b)) * HID;
    size_t so = ((size_t)(b * LM + pos)) * D2 + dir * HID;
    for (int u = tid; u < HID; u += 256) {
        float gi = g0[u]           + g1[u]           + bias[u];
        float gf = g0[HID + u]     + g1[HID + u]     + bias[HID + u];
        float gu = g0[2 * HID + u] + g1[2 * HID + u] + bias[2 * HID + u];
        float go = g0[3 * HID + u] + g1[3 * HID + u] + bias[3 * HID + u];
        float c = sigm(gf) * cc[u] + sigm(gi) * tanhf(gu);
        float h = sigm(go) * tanhf(c);
        cc[u] = c; c_seq[so + u] = c;
        unsigned short hb = bf16_rne(h);
        unsigned short hl2 = bf16_rne(h - bf16_tof(hb));
        hch[u] = hb; hcl[u] = hl2;
        h_hi[so + u] = hb; h_lo[so + u] = hl2;
    }
}

// ---------------------------------------------------------------------------
// Pair GEMM: gload_lds staging, double-buffered LDS, 1 barrier/K-step.
// Tile BM x 128, 4 waves (2x2). LDS rows 32 shorts (64B), XOR-swizzled.
// LOOPRT=false: 3D grid (sub, col, kz) — initial pass.
// LOOPRT=true:  2D grid (col, kz); ONE block owns each W slice and loops
//               over row-tiles internally (W fetched into exactly one L2).
// ---------------------------------------------------------------------------
template<int BM, int KTOT, bool LOOPRT>
__global__ __launch_bounds__(256)
void gemm_pairs_g(const int4* __restrict__ rowlist, int nrows_lit,
                  const int* __restrict__ nrows_ptr, int cap,
                  const unsigned short* __restrict__ h_hi,
                  const unsigned short* __restrict__ h_lo,
                  const unsigned short* __restrict__ w_hi,
                  const unsigned short* __restrict__ w_lo,
                  float* __restrict__ vbuf)
{
    constexpr int WROWS = BM / 2;
    constexpr int FM = WROWS / 16;
    constexpr int NRS = BM / 64;
    constexpr int SA = BM * 32;
    constexpr int SB = 128 * 32;
    constexpr int BUF = 2 * SA + 2 * SB;

    int nrows = nrows_ptr ? *nrows_ptr : nrows_lit;

    int yc, kz, rt0, rtN;
    if constexpr (LOOPRT) {
        yc = blockIdx.x; kz = blockIdx.y;
        rt0 = 0; rtN = (nrows + BM - 1) / BM;
    } else {
        yc = blockIdx.y; kz = blockIdx.z;
        rt0 = blockIdx.x; rtN = rt0 + 1;
        if (rt0 * BM >= nrows) return;
    }

    const int col0 = yc * 128;
    const int kbeg = kz * KTOT;
    const int kend = kbeg + KTOT;
    float* vout = vbuf + (size_t)kz * cap * D5;

    const int tid = threadIdx.x, lane = tid & 63, w = tid >> 6;
    const int wm = w >> 1, wn = w & 1;

    __shared__ __align__(16) unsigned short smem[2 * BUF];

    const int sz8 = ((lane & 3) ^ ((lane >> 3) & 3)) * 8;
    size_t colOff[2];
#pragma unroll
    for (int cs = 0; cs < 2; ++cs)
        colOff[cs] = ((size_t)(col0 + (w + 4 * cs) * 16 + (lane >> 2))) * H4;

    const int rsw = ((lane >> 4) ^ ((lane >> 1) & 3)) * 8;
    const int a_off = (wm * WROWS + (lane & 15)) * 32 + rsw;
    const int b_off = 2 * SA + (wn * 64 + (lane & 15)) * 32 + rsw;

    for (int rt = rt0; rt < rtN; ++rt) {
        const int row0 = rt * BM;

        size_t offL[NRS], offR[NRS];
#pragma unroll
        for (int rs = 0; rs < NRS; ++rs) {
            int rr = row0 + (w + 4 * rs) * 16 + (lane >> 2);
            if (rr > nrows - 1) rr = nrows - 1;
            int4 e = rowlist[rr];
            if (e.x < 0) { e.x = 0; e.y = 0; e.z = 1; }
            offL[rs] = ((size_t)(e.x * LM + e.y)) * D2;
            offR[rs] = ((size_t)(e.x * LM + e.z)) * D2;
        }

        auto stage = [&](int d, int k) {
            unsigned short* sb = smem + d * BUF;
#pragma unroll
            for (int j = 0; j < 2 * NRS; ++j) {
                const int pl = j / NRS, rs = j % NRS;
                const int g2 = w + 4 * rs;
                const unsigned short* hb = pl ? h_lo : h_hi;
                size_t off = (k < D2) ? (offL[rs] + k) : (offR[rs] + (k - D2));
                gload16(hb + off + sz8, sb + pl * SA + g2 * 512);
            }
#pragma unroll
            for (int j = 0; j < 4; ++j) {
                const int pl = j >> 1, cs = j & 1;
                const int g2 = w + 4 * cs;
                const unsigned short* wb = pl ? w_lo : w_hi;
                gload16(wb + colOff[cs] + k + sz8, sb + 2 * SA + pl * SB + g2 * 512);
            }
        };

        f32x4 acc[FM][4];
#pragma unroll
        for (int i = 0; i < FM; ++i)
#pragma unroll
            for (int j = 0; j < 4; ++j) acc[i][j] = (f32x4){0.f, 0.f, 0.f, 0.f};

        stage(0, kbeg);
        __syncthreads();
        int cur = 0;
        for (int k0 = kbeg; k0 < kend; k0 += 32) {
            if (k0 + 32 < kend) stage(cur ^ 1, k0 + 32);
            const unsigned short* sb = smem + cur * BUF;
            bf16x8 ah[FM], al[FM];
#pragma unroll
            for (int fm = 0; fm < FM; ++fm) {
                ah[fm] = *(const bf16x8*)&sb[a_off + fm * 512];
                al[fm] = *(const bf16x8*)&sb[SA + a_off + fm * 512];
            }
#pragma unroll
            for (int fn = 0; fn < 4; ++fn) {
                bf16x8 bh = *(const bf16x8*)&sb[b_off + fn * 512];
                bf16x8 bl = *(const bf16x8*)&sb[SB + b_off + fn * 512];
#pragma unroll
                for (int fm = 0; fm < FM; ++fm) {
                    acc[fm][fn] = __builtin_amdgcn_mfma_f32_16x16x32_bf16(ah[fm], bh, acc[fm][fn], 0, 0, 0);
                    acc[fm][fn] = __builtin_amdgcn_mfma_f32_16x16x32_bf16(ah[fm], bl, acc[fm][fn], 0, 0, 0);
                    acc[fm][fn] = __builtin_amdgcn_mfma_f32_16x16x32_bf16(al[fm], bh, acc[fm][fn], 0, 0, 0);
                }
            }
            __syncthreads();
            cur ^= 1;
        }

#pragma unroll
        for (int fm = 0; fm < FM; ++fm) {
            int rbase = row0 + wm * WROWS + fm * 16 + (lane >> 4) * 4;
#pragma unroll
            for (int fn = 0; fn < 4; ++fn) {
                int c = col0 + wn * 64 + fn * 16 + (lane & 15);
#pragma unroll
                for (int q = 0; q < 4; ++q) {
                    int r2 = rbase + q;
                    if (r2 < nrows) vout[(size_t)r2 * D5 + c] = acc[fm][fn][q];
                }
            }
        }
    }
}

// ---------------------------------------------------------------------------
// Gates for one rowlist entry (all 256 threads). Sums nz split-K partials.
// ---------------------------------------------------------------------------
__device__ __forceinline__ void gates_row(int row, int4 e,
    const float* __restrict__ v_buf, int cap, int nz,
    const float* __restrict__ b_comp, const float* __restrict__ c_seq,
    const float* __restrict__ w_q,
    float* __restrict__ nh_cand, float* __restrict__ nc_cand,
    float* __restrict__ logits)
{
    int b = e.x, sL = e.y, sR = e.z;
    int cslot = e.w & 0xffff, plog = e.w >> 16;
    const float* v = v_buf + (size_t)row * D5;
    const size_t zstride = (size_t)cap * D5;
    const float* cl = c_seq + ((size_t)(b * LM + sL)) * D2;
    const float* cr = c_seq + ((size_t)(b * LM + sR)) * D2;
    float* nh = nh_cand + ((size_t)(b * 15 + cslot)) * D2;
    float* nc = nc_cand + ((size_t)(b * 15 + cslot)) * D2;

    float part = 0.f;
    for (int d = threadIdx.x; d < D2; d += 256) {
        float gi  = v[d];
        float gfl = v[D2 + d];
        float gfr = v[2 * D2 + d];
        float gu  = v[3 * D2 + d];
        float go  = v[4 * D2 + d];
        for (int z = 1; z < nz; ++z) {
            const float* vz = v + z * zstride;
            gi += vz[d]; gfl += vz[D2 + d]; gfr += vz[2 * D2 + d];
            gu += vz[3 * D2 + d]; go += vz[4 * D2 + d];
        }
        gi += b_comp[d]; gfl += b_comp[D2 + d]; gfr += b_comp[2 * D2 + d];
        gu += b_comp[3 * D2 + d]; go += b_comp[4 * D2 + d];
        float c = cl[d] * sigm(gfl + 1.0f) + cr[d] * sigm(gfr + 1.0f) + tanhf(gu) * sigm(gi);
        float h = sigm(go) * tanhf(c);
        nc[d] = c; nh[d] = h;
        part += h * w_q[d];
    }
    for (int o = 32; o > 0; o >>= 1) part += __shfl_down(part, o);
    __shared__ float wsum[4];
    if ((threadIdx.x & 63) == 0) wsum[threadIdx.x >> 6] = part;
    __syncthreads();
    if (threadIdx.x == 0) logits[b * 16 + plog] = wsum[0] + wsum[1] + wsum[2] + wsum[3];
    __syncthreads();
}

// ---------------------------------------------------------------------------
__global__ __launch_bounds__(256)
void gates_logits(const int4* __restrict__ rowlist, int nrows_lit,
                  const int* __restrict__ nrows_ptr,
                  const float* __restrict__ v_buf, int cap, int nz,
                  const float* __restrict__ b_comp,
                  const float* __restrict__ c_seq, const float* __restrict__ w_q,
                  float* __restrict__ nh, float* __restrict__ nc,
                  float* __restrict__ logits)
{
    int nrows = nrows_ptr ? *nrows_ptr : nrows_lit;
    int row = blockIdx.x;
    if (row >= nrows) return;
    int4 e = rowlist[row];
    if (e.x < 0) return;
    gates_row(row, e, v_buf, cap, nz, b_comp, c_seq, w_q, nh, nc, logits);
}

// ---------------------------------------------------------------------------
// Merge body for batch b (all 256 threads). Records per-batch slots
// (slotR: compacted row idx or -1; slotE: the rowlist entry).
// ---------------------------------------------------------------------------
__device__ void merge_body(int iter, int b, const int* __restrict__ lengths,
                  float* __restrict__ c_seq,
                  const float* __restrict__ nh_cand, const float* __restrict__ nc_cand,
                  float* __restrict__ logits, int* __restrict__ pos_idx,
                  int* __restrict__ pair_idx, int4* __restrict__ rowlist_out,
                  int* __restrict__ rcount, int4* __restrict__ slotE,
                  int* __restrict__ slotR,
                  unsigned short* __restrict__ h_hi, unsigned short* __restrict__ h_lo)
{
    int tid = threadIdx.x;
    int M = 15 - iter;
    int len = lengths[b];
    bool act = (iter + 1) < len;

    __shared__ float sl[16];
    __shared__ int sp[16], sq[16];
    __shared__ int s_sel;

    if (tid <= M) sp[tid] = pos_idx[b * 16 + tid];
    if (tid < M) { sq[tid] = pair_idx[b * 16 + tid]; sl[tid] = logits[b * 16 + tid]; }
    __syncthreads();

    if (tid == 0) {
        int sel = -1;
        if (act) {
            float best = -INFINITY; sel = 0;
            for (int p2 = 0; p2 < M; ++p2) {
                float mv = ((iter + 1 + p2) < len) ? sl[p2] : (sl[p2] - 10000.0f);
                if (mv > best) { best = mv; sel = p2; }
            }
        }
        s_sel = sel;
    }
    __syncthreads();
    int sel = s_sel;

    if (sel >= 0) {
        int slotL = sp[sel];
        int cslot = sq[sel];
        const float* nh = nh_cand + ((size_t)(b * 15 + cslot)) * D2;
        const float* nc = nc_cand + ((size_t)(b * 15 + cslot)) * D2;
        float* cd = c_seq + ((size_t)(b * LM + slotL)) * D2;
        unsigned short* hh = h_hi + ((size_t)(b * LM + slotL)) * D2;
        unsigned short* hl = h_lo + ((size_t)(b * LM + slotL)) * D2;
        for (int d = tid; d < D2; d += 256) {
            float hv = nh[d];
            cd[d] = nc[d];
            unsigned short hb = bf16_rne(hv);
            hh[d] = hb;
            hl[d] = bf16_rne(hv - bf16_tof(hb));
        }

        if (tid == 0) {
            for (int p2 = sel + 1; p2 < M; ++p2) sp[p2] = sp[p2 + 1];
            for (int p2 = sel + 1; p2 < M - 1; ++p2) { sq[p2] = sq[p2 + 1]; sl[p2] = sl[p2 + 1]; }
            int Mn = M - 1;
            if (iter < 14) {
                int s0 = -1, s1 = -1;
                if (sel - 1 >= 0) {
                    int4 e0 = make_int4(b, sp[sel - 1], sp[sel], sq[sel - 1] | ((sel - 1) << 16));
                    s0 = atomicAdd(rcount, 1);
                    rowlist_out[s0] = e0;
                    slotE[2 * b] = e0;
                }
                if (sel <= Mn - 1) {
                    int4 e1 = make_int4(b, sp[sel], sp[sel + 1], sq[sel] | (sel << 16));
                    s1 = atomicAdd(rcount, 1);
                    rowlist_out[s1] = e1;
                    slotE[2 * b + 1] = e1;
                }
                slotR[2 * b] = s0; slotR[2 * b + 1] = s1;
            }
            for (int p2 = 0; p2 < M; ++p2) pos_idx[b * 16 + p2] = sp[p2];
            for (int p2 = 0; p2 < Mn; ++p2) { pair_idx[b * 16 + p2] = sq[p2]; logits[b * 16 + p2] = sl[p2]; }
        }
    } else {
        if (tid == 0 && iter < 14) { slotR[2 * b] = -1; slotR[2 * b + 1] = -1; }
    }
}

__global__ __launch_bounds__(256)
void merge_kernel(int iter, const int* __restrict__ lens, float* __restrict__ c_seq,
                  const float* __restrict__ nh, const float* __restrict__ nc,
                  float* __restrict__ logits, int* __restrict__ pos, int* __restrict__ pair,
                  int4* __restrict__ rowlist_out, int* __restrict__ rcount,
                  int4* __restrict__ slotE, int* __restrict__ slotR,
                  unsigned short* __restrict__ h_hi, unsigned short* __restrict__ h_lo)
{
    merge_body(iter, blockIdx.x, lens, c_seq, nh, nc, logits, pos, pair,
               rowlist_out, rcount, slotE, slotR, h_hi, h_lo);
}

// ---------------------------------------------------------------------------
// Fused gates(it) + merge(it+1): the two candidate rows are processed
// CONCURRENTLY by half-blocks (128 threads each), then the merge runs with
// the full block. No cross-block dependency inside the kernel.
// ---------------------------------------------------------------------------
__global__ __launch_bounds__(256)
void gates_merge(int it, const int* __restrict__ lens,
                 const float* __restrict__ vbuf, int cap, int nz,
                 const float* __restrict__ b_comp, float* __restrict__ c_seq,
                 const float* __restrict__ w_q,
                 float* __restrict__ nh_cand, float* __restrict__ nc_cand,
                 float* __restrict__ logits,
                 int* __restrict__ pos, int* __restrict__ pair,
                 int4* __restrict__ rowlist_out, int* __restrict__ rc_next,
                 int4* __restrict__ slotE, int* __restrict__ slotR,
                 unsigned short* __restrict__ h_hi, unsigned short* __restrict__ h_lo)
{
    int b = blockIdx.x;
    int tid = threadIdx.x;
    int slot = tid >> 7, tid2 = tid & 127;
    int row = slotR[2 * b + slot];
    int4 e = slotE[2 * b + slot];

    __shared__ float wsum2[2][2];

    float part = 0.f;
    if (row >= 0) {
        int cslot = e.w & 0xffff;
        const float* v = vbuf + (size_t)row * D5;
        const size_t zstride = (size_t)cap * D5;
        const float* cl = c_seq + ((size_t)(b * LM + e.y)) * D2;
        const float* cr = c_seq + ((size_t)(b * LM + e.z)) * D2;
        float* nh = nh_cand + ((size_t)(b * 15 + cslot)) * D2;
        float* nc = nc_cand + ((size_t)(b * 15 + cslot)) * D2;
        for (int d = tid2; d < D2; d += 128) {
            float gi  = v[d];
            float gfl = v[D2 + d];
            float gfr = v[2 * D2 + d];
            float gu  = v[3 * D2 + d];
            float go  = v[4 * D2 + d];
            for (int z = 1; z < nz; ++z) {
                const float* vz = v + z * zstride;
                gi += vz[d]; gfl += vz[D2 + d]; gfr += vz[2 * D2 + d];
                gu += vz[3 * D2 + d]; go += vz[4 * D2 + d];
            }
            gi += b_comp[d]; gfl += b_comp[D2 + d]; gfr += b_comp[2 * D2 + d];
            gu += b_comp[3 * D2 + d]; go += b_comp[4 * D2 + d];
            float c = cl[d] * sigm(gfl + 1.0f) + cr[d] * sigm(gfr + 1.0f) + tanhf(gu) * sigm(gi);
            float h = sigm(go) * tanhf(c);
            nc[d] = c; nh[d] = h;
            part += h * w_q[d];
        }
    }
    for (int o = 32; o > 0; o >>= 1) part += __shfl_down(part, o);
    if ((tid2 & 63) == 0) wsum2[slot][tid2 >> 6] = part;
    __syncthreads();
    if (row >= 0 && tid2 == 0) {
        int plog = e.w >> 16;
        logits[b * 16 + plog] = wsum2[slot][0] + wsum2[slot][1];
    }
    __syncthreads();

    merge_body(it + 1, b, lens, c_seq, nh_cand, nc_cand, logits, pos, pair,
               rowlist_out, rc_next, slotE, slotR, h_hi, h_lo);
}

__global__ __launch_bounds__(256)
void copy_out(const unsigned short* __restrict__ h_hi,
              const unsigned short* __restrict__ h_lo, float* __restrict__ out)
{
    int b = blockIdx.x;
    size_t base = (size_t)(b * LM) * D2;
    for (int d = threadIdx.x; d < D2; d += 256)
        out[(size_t)b * D2 + d] = bf16_tof(h_hi[base + d]) + bf16_tof(h_lo[base + d]);
}

// ---------------------------------------------------------------------------
extern "C" void kernel_launch(void* const* d_in, const int* in_sizes, int n_in,
                              void* d_out, int out_size, void* d_ws, size_t ws_size,
                              hipStream_t stream)
{
    const float* x      = (const float*)d_in[0];
    const int*   lens   = (const int*)  d_in[1];
    const float* w_ih_f = (const float*)d_in[2];
    const float* w_hh_f = (const float*)d_in[3];
    const float* b_f    = (const float*)d_in[4];
    const float* w_ih_b = (const float*)d_in[5];
    const float* w_hh_b = (const float*)d_in[6];
    const float* b_b    = (const float*)d_in[7];
    const float* w_comp = (const float*)d_in[8];
    const float* b_comp = (const float*)d_in[9];
    const float* w_q    = (const float*)d_in[10];
    float* out = (float*)d_out;

    char* p = (char*)d_ws;
    auto alloc = [&](size_t bytes) {
        char* q = p; p += (bytes + 255) & ~(size_t)255; return q;
    };
    float* c_seq = (float*)alloc((size_t)NB * LM * D2 * 4);
    float* nh    = (float*)alloc((size_t)NB * 15 * D2 * 4);
    float* nc    = (float*)alloc((size_t)NB * 15 * D2 * 4);
    unsigned short* h_hi = (unsigned short*)alloc((size_t)NB * LM * D2 * 2);
    unsigned short* h_lo = (unsigned short*)alloc((size_t)NB * LM * D2 * 2);
    unsigned short* w_hi = (unsigned short*)alloc((size_t)D5 * H4 * 2);
    unsigned short* w_lo = (unsigned short*)alloc((size_t)D5 * H4 * 2);
    unsigned short* x_hi = (unsigned short*)alloc((size_t)NB * LM * HID * 2);
    unsigned short* x_lo = (unsigned short*)alloc((size_t)NB * LM * HID * 2);
    unsigned short* wl_hi = (unsigned short*)alloc((size_t)2 * H4 * 1024 * 2);
    unsigned short* wl_lo = (unsigned short*)alloc((size_t)2 * H4 * 1024 * 2);
    unsigned short* hc_hi = (unsigned short*)alloc((size_t)2 * NB * HID * 2);
    unsigned short* hc_lo = (unsigned short*)alloc((size_t)2 * NB * HID * 2);
    float* ccur  = (float*)alloc((size_t)2 * NB * HID * 4);
    float* logits = (float*)alloc((size_t)NB * 16 * 4);
    int*   pos    = (int*)alloc((size_t)NB * 16 * 4);
    int*   pair   = (int*)alloc((size_t)NB * 16 * 4);
    int4*  rowlist0   = (int4*)alloc((size_t)NPAIR0 * 16);
    int4*  rowlist_c  = (int4*)alloc((size_t)NPAIR0 * 16);
    int4*  rowlist_inc= (int4*)alloc((size_t)INC_CAP * 16);
    int4*  slotE  = (int4*)alloc((size_t)2 * NB * 16);
    int*   slotR  = (int*)alloc((size_t)2 * NB * 4);
    int*   rcount = (int*)alloc(16 * 4);
    // tail: gbuf (LSTM partials, 8.4MB) then reused as vbuf (pairs)
    char* tail = p;
    float* gbuf = (float*)tail;
    float* vbuf = (float*)tail;

    size_t used = (size_t)(tail - (char*)d_ws);
    size_t avail = (ws_size > used) ? (ws_size - used) : 0;
    size_t maxc = avail / ((size_t)D5 * 4);
    if (maxc > (size_t)NPAIR0) maxc = NPAIR0;
    int chunk = ((int)maxc) & ~127;
    if (chunk < 2048) chunk = 2048;   // need >= 4*INC_CAP rows of vbuf anyway

    hipMemsetAsync(rcount, 0, 64, stream);
    init_kernel<<<dim3(NB), dim3(256), 0, stream>>>(lens, ccur, hc_hi, hc_lo, pos, pair,
                                                    rowlist0, rowlist_c, rcount, logits);
    split_w<<<dim3(2048), dim3(256), 0, stream>>>((const float4*)w_comp, w_hi, w_lo, (int)((size_t)D5 * H4 / 4));
    split_w<<<dim3(1024), dim3(256), 0, stream>>>((const float4*)x, x_hi, x_lo, (int)((size_t)NB * LM * HID / 4));
    pack_lstm_w<<<dim3(1024), dim3(256), 0, stream>>>(w_ih_f, w_hh_f, w_ih_b, w_hh_b, wl_hi, wl_lo);

    // ---- bidirectional LSTM, 16 sequential steps (split-K x2, grouped) ----
    for (int t = 0; t < 16; ++t) {
        gemm_lstm_g<<<dim3(256), dim3(256), 0, stream>>>(
            t, lens, x_hi, x_lo, hc_hi, hc_lo, wl_hi, wl_lo, gbuf);
        lstm_gate<<<dim3(NB, 2), dim3(256), 0, stream>>>(
            t, lens, b_f, b_b, gbuf, ccur, hc_hi, hc_lo, h_hi, h_lo, c_seq);
    }

    // ---- iter 0: candidates + logits (length-compacted if vbuf fits) ----
    if (chunk >= NPAIR0) {
        gemm_pairs_g<128, 2048, false><<<dim3(30, 40, 1), dim3(256), 0, stream>>>(
            rowlist_c, NPAIR0, (const int*)(rcount + 15), 0,
            h_hi, h_lo, w_hi, w_lo, vbuf);
        gates_logits<<<dim3(NPAIR0), dim3(256), 0, stream>>>(
            rowlist_c, NPAIR0, (const int*)(rcount + 15),
            vbuf, 0, 1, b_comp, c_seq, w_q, nh, nc, logits);
    } else {
        for (int off = 0; off < NPAIR0; off += chunk) {
            int rows = NPAIR0 - off; if (rows > chunk) rows = chunk;
            int RT = (rows + 127) >> 7;
            gemm_pairs_g<128, 2048, false><<<dim3(RT, 40, 1), dim3(256), 0, stream>>>(
                rowlist0 + off, rows, (const int*)nullptr, 0,
                h_hi, h_lo, w_hi, w_lo, vbuf);
            gates_logits<<<dim3(rows), dim3(256), 0, stream>>>(
                rowlist0 + off, rows, (const int*)nullptr,
                vbuf, 0, 1, b_comp, c_seq, w_q, nh, nc, logits);
        }
    }

    // ---- merge(0), then 14 iterations of { gemm ; gates+merge } ----
    merge_kernel<<<dim3(NB), dim3(256), 0, stream>>>(
        0, lens, c_seq, nh, nc, logits, pos, pair,
        rowlist_inc, rcount + 0, slotE, slotR, h_hi, h_lo);
    for (int it = 0; it < 14; ++it) {
        gemm_pairs_g<128, 512, true><<<dim3(40, 4), dim3(256), 0, stream>>>(
            rowlist_inc, 0, (const int*)(rcount + it), INC_CAP,
            h_hi, h_lo, w_hi, w_lo, vbuf);
        gates_merge<<<dim3(NB), dim3(256), 0, stream>>>(
            it, lens, vbuf, INC_CAP, 4, b_comp, c_seq, w_q, nh, nc, logits,
            pos, pair, rowlist_inc, rcount + it + 1, slotE, slotR, h_hi, h_lo);
    }

    copy_out<<<dim3(NB), dim3(256), 0, stream>>>(h_hi, h_lo, out);
}

// Round 13
// 1368.677 us; speedup vs baseline: 1.0490x; 1.0490x over previous
//
#include <hip/hip_runtime.h>
#include <math.h>

#define NB 256
#define LM 16
#define HID 512
#define H4 2048
#define D2 1024
#define D5 5120
#define NPAIR0 3840   // 256*15
#define INC_CAP 512   // max incremental rows (2 per batch)

typedef __attribute__((ext_vector_type(8))) short bf16x8;
typedef __attribute__((ext_vector_type(4))) float f32x4;

__device__ __forceinline__ float sigm(float x) { return 1.0f / (1.0f + expf(-x)); }

__device__ __forceinline__ unsigned short bf16_rne(float f) {
    union { float f; unsigned u; } v; v.f = f;
    unsigned u = v.u;
    return (unsigned short)((u + 0x7fffu + ((u >> 16) & 1u)) >> 16);
}
__device__ __forceinline__ float bf16_tof(unsigned short h) {
    union { unsigned u; float f; } v; v.u = ((unsigned)h) << 16;
    return v.f;
}

// async global->LDS, 16B per lane; dest = wave-uniform base + lane*16
__device__ __forceinline__ void gload16(const unsigned short* g, unsigned short* l) {
    __builtin_amdgcn_global_load_lds(
        (const __attribute__((address_space(1))) void*)(const void*)g,
        (__attribute__((address_space(3))) void*)(void*)l, 16, 0, 0);
}

// ---------------------------------------------------------------------------
// init: zero LSTM state, slot maps, uncompacted + length-compacted rowlists,
// logits = -1e30 (missing pairs stay masked). rcount must be pre-zeroed.
// Compacted count lives in rcount[15]; merges own rcount[0..14].
// ---------------------------------------------------------------------------
__global__ __launch_bounds__(256)
void init_kernel(const int* __restrict__ lens, float* ccur,
                 unsigned short* hc_hi, unsigned short* hc_lo,
                 int* pos, int* pair, int4* rowlist0, int4* rowlist_c,
                 int* rcount, float* logits)
{
    int b = blockIdx.x, tid = threadIdx.x;
    for (int u = tid; u < HID; u += 256) {
        ccur[(size_t)b * HID + u] = 0.f;
        ccur[((size_t)NB + b) * HID + u] = 0.f;
        hc_hi[(size_t)b * HID + u] = 0;
        hc_hi[((size_t)NB + b) * HID + u] = 0;
        hc_lo[(size_t)b * HID + u] = 0;
        hc_lo[((size_t)NB + b) * HID + u] = 0;
    }
    if (tid < 16) { pos[b * 16 + tid] = tid; pair[b * 16 + tid] = tid; logits[b * 16 + tid] = -1e30f; }
    if (tid < 15) rowlist0[b * 15 + tid] = make_int4(b, tid, tid + 1, tid | (tid << 16));
    __shared__ int sbase;
    int len = lens[b];
    if (tid == 0) sbase = atomicAdd(rcount + 15, len - 1);
    __syncthreads();
    if (tid < len - 1) rowlist_c[sbase + tid] = make_int4(b, tid, tid + 1, tid | (tid << 16));
}

// ---------------------------------------------------------------------------
__global__ __launch_bounds__(256)
void split_w(const float4* __restrict__ w, unsigned short* __restrict__ hi,
             unsigned short* __restrict__ lo, int n4)
{
    for (int i = blockIdx.x * 256 + threadIdx.x; i < n4; i += gridDim.x * 256) {
        float4 f = w[i];
        ushort4 h, l;
        h.x = bf16_rne(f.x); l.x = bf16_rne(f.x - bf16_tof(h.x));
        h.y = bf16_rne(f.y); l.y = bf16_rne(f.y - bf16_tof(h.y));
        h.z = bf16_rne(f.z); l.z = bf16_rne(f.z - bf16_tof(h.z));
        h.w = bf16_rne(f.w); l.w = bf16_rne(f.w - bf16_tof(h.w));
        ((ushort4*)hi)[i] = h;
        ((ushort4*)lo)[i] = l;
    }
}

// ---------------------------------------------------------------------------
__global__ __launch_bounds__(256)
void pack_lstm_w(const float* __restrict__ w_ih_f, const float* __restrict__ w_hh_f,
                 const float* __restrict__ w_ih_b, const float* __restrict__ w_hh_b,
                 unsigned short* __restrict__ wl_hi, unsigned short* __restrict__ wl_lo)
{
    const int total4 = 2 * H4 * 256;
    for (int i = blockIdx.x * 256 + threadIdx.x; i < total4; i += gridDim.x * 256) {
        int k4 = i & 255;
        int j = (i >> 8) & 2047;
        int dir = i >> 19;
        const float* wih = dir ? w_ih_b : w_ih_f;
        const float* whh = dir ? w_hh_b : w_hh_f;
        float4 f = (k4 < 128) ? *(const float4*)(wih + (size_t)j * HID + k4 * 4)
                              : *(const float4*)(whh + (size_t)j * HID + (k4 - 128) * 4);
        ushort4 h, l;
        h.x = bf16_rne(f.x); l.x = bf16_rne(f.x - bf16_tof(h.x));
        h.y = bf16_rne(f.y); l.y = bf16_rne(f.y - bf16_tof(h.y));
        h.z = bf16_rne(f.z); l.z = bf16_rne(f.z - bf16_tof(h.z));
        h.w = bf16_rne(f.w); l.w = bf16_rne(f.w - bf16_tof(h.w));
        ((ushort4*)wl_hi)[i] = h;
        ((ushort4*)wl_lo)[i] = l;
    }
}

// ---------------------------------------------------------------------------
// LSTM step GEMM: gload_lds staging, double-buffered LDS, swizzled.
// Split-K x2 + grouped 1D mapping (round-11 proven version).
// ---------------------------------------------------------------------------
__global__ __launch_bounds__(256)
void gemm_lstm_g(int t, const int* __restrict__ lens,
                 const unsigned short* __restrict__ x_hi, const unsigned short* __restrict__ x_lo,
                 const unsigned short* __restrict__ hc_hi, const unsigned short* __restrict__ hc_lo,
                 const unsigned short* __restrict__ wl_hi, const unsigned short* __restrict__ wl_lo,
                 float* __restrict__ gbuf)
{
    constexpr int SA = 64 * 32;        // shorts per A plane
    constexpr int SB = 128 * 32;       // shorts per B plane
    constexpr int BUF = 2 * SA + 2 * SB;

    const int bid = blockIdx.x;
    const int x8 = bid & 7, r = bid >> 3;
    const int sub = r & 3, gq = r >> 2;
    const int g = x8 + 8 * gq;         // 0..63
    const int row0 = sub * 64;
    const int col0 = (g & 15) * 128;
    const int zz = g >> 4;
    const int dir = zz & 1;
    const int kz = zz >> 1;
    const int kbeg = kz * 512, kend = kbeg + 512;
    float* gout = gbuf + (size_t)kz * 2 * NB * H4;

    const int tid = threadIdx.x, lane = tid & 63, w = tid >> 6;
    const int wm = w >> 1, wn = w & 1;

    __shared__ __align__(16) unsigned short smem[2 * BUF];

    const int sz8 = ((lane & 3) ^ ((lane >> 3) & 3)) * 8;  // swizzled source part
    const int b0 = row0 + w * 16 + (lane >> 2);
    const int len = lens[b0];
    const int trow = dir ? ((t < len) ? (len - 1 - t) : t) : t;
    const size_t xoff = ((size_t)(b0 * LM + trow)) * HID;
    const size_t hoff = ((size_t)(dir * NB + b0)) * HID;

    size_t colOff[2];
#pragma unroll
    for (int cs = 0; cs < 2; ++cs)
        colOff[cs] = ((size_t)(dir * H4 + col0 + (w + 4 * cs) * 16 + (lane >> 2))) * 1024;

    auto stage = [&](int d, int k) {
        unsigned short* sb = smem + d * BUF;
        const unsigned short* sh = (k < HID) ? (x_hi + xoff + k) : (hc_hi + hoff + (k - HID));
        gload16(sh + sz8, sb + w * 512);
        const unsigned short* sl = (k < HID) ? (x_lo + xoff + k) : (hc_lo + hoff + (k - HID));
        gload16(sl + sz8, sb + SA + w * 512);
#pragma unroll
        for (int j = 0; j < 4; ++j) {
            const int pl = j >> 1, cs = j & 1;
            const unsigned short* wb = pl ? wl_lo : wl_hi;
            gload16(wb + colOff[cs] + k + sz8, sb + 2 * SA + pl * SB + (w + 4 * cs) * 512);
        }
    };

    f32x4 acc[2][4];
#pragma unroll
    for (int i = 0; i < 2; ++i)
#pragma unroll
        for (int j = 0; j < 4; ++j) acc[i][j] = (f32x4){0.f, 0.f, 0.f, 0.f};

    const int rsw = ((lane >> 4) ^ ((lane >> 1) & 3)) * 8;   // swizzled read slot
    const int a_off = (wm * 32 + (lane & 15)) * 32 + rsw;
    const int b_off = 2 * SA + (wn * 64 + (lane & 15)) * 32 + rsw;

    stage(0, kbeg);
    __syncthreads();
    int cur = 0;
    for (int k0 = kbeg; k0 < kend; k0 += 32) {
        if (k0 + 32 < kend) stage(cur ^ 1, k0 + 32);
        const unsigned short* sb = smem + cur * BUF;
        bf16x8 ah[2], al[2];
#pragma unroll
        for (int fm = 0; fm < 2; ++fm) {
            ah[fm] = *(const bf16x8*)&sb[a_off + fm * 512];
            al[fm] = *(const bf16x8*)&sb[SA + a_off + fm * 512];
        }
#pragma unroll
        for (int fn = 0; fn < 4; ++fn) {
            bf16x8 bh = *(const bf16x8*)&sb[b_off + fn * 512];
            bf16x8 bl = *(const bf16x8*)&sb[SB + b_off + fn * 512];
#pragma unroll
            for (int fm = 0; fm < 2; ++fm) {
                acc[fm][fn] = __builtin_amdgcn_mfma_f32_16x16x32_bf16(ah[fm], bh, acc[fm][fn], 0, 0, 0);
                acc[fm][fn] = __builtin_amdgcn_mfma_f32_16x16x32_bf16(ah[fm], bl, acc[fm][fn], 0, 0, 0);
                acc[fm][fn] = __builtin_amdgcn_mfma_f32_16x16x32_bf16(al[fm], bh, acc[fm][fn], 0, 0, 0);
            }
        }
        __syncthreads();
        cur ^= 1;
    }

#pragma unroll
    for (int fm = 0; fm < 2; ++fm) {
        int rbase = row0 + wm * 32 + fm * 16 + (lane >> 4) * 4;
#pragma unroll
        for (int fn = 0; fn < 4; ++fn) {
            int c = col0 + wn * 64 + fn * 16 + (lane & 15);
#pragma unroll
            for (int q = 0; q < 4; ++q)
                gout[((size_t)(dir * NB + rbase + q)) * H4 + c] = acc[fm][fn][q];
        }
    }
}

// ---------------------------------------------------------------------------
__global__ __launch_bounds__(256)
void lstm_gate(int t, const int* __restrict__ lengths,
               const float* __restrict__ b_f, const float* __restrict__ b_b,
               const float* __restrict__ g_buf, float* __restrict__ ccur,
               unsigned short* __restrict__ hc_hi, unsigned short* __restrict__ hc_lo,
               unsigned short* __restrict__ h_hi, unsigned short* __restrict__ h_lo,
               float* __restrict__ c_seq)
{
    int b = blockIdx.x, dir = blockIdx.y, tid = threadIdx.x;
    const float* bias = dir ? b_b : b_f;
    int len = lengths[b];
    int pos = dir ? ((t < len) ? (len - 1 - t) : t) : t;
    const float* g0 = g_buf + ((size_t)(dir * NB + b)) * H4;
    const float* g1 = g0 + (size_t)2 * NB * H4;
    float* cc = ccur + ((size_t)(dir * NB + b)) * HID;
    unsigned short* hch = hc_hi + ((size_t)(dir * NB + b)) * HID;
    unsigned short* hcl = hc_lo + ((size_t)(dir * NB + b)) * HID;
    size_t so = ((size_t)(b * LM + pos)) * D2 + dir * HID;
    for (int u = tid; u < HID; u += 256) {
        float gi = g0[u]           + g1[u]           + bias[u];
        float gf = g0[HID + u]     + g1[HID + u]     + bias[HID + u];
        float gu = g0[2 * HID + u] + g1[2 * HID + u] + bias[2 * HID + u];
        float go = g0[3 * HID + u] + g1[3 * HID + u] + bias[3 * HID + u];
        float c = sigm(gf) * cc[u] + sigm(gi) * tanhf(gu);
        float h = sigm(go) * tanhf(c);
        cc[u] = c; c_seq[so + u] = c;
        unsigned short hb = bf16_rne(h);
        unsigned short hl2 = bf16_rne(h - bf16_tof(hb));
        hch[u] = hb; hcl[u] = hl2;
        h_hi[so + u] = hb; h_lo[so + u] = hl2;
    }
}

// ---------------------------------------------------------------------------
// Pair GEMM (initial pass): BM x 128 tile, 4 waves, 3D grid. Round-11 proven.
// ---------------------------------------------------------------------------
template<int BM, int KTOT>
__global__ __launch_bounds__(256)
void gemm_pairs_g(const int4* __restrict__ rowlist, int nrows_lit,
                  const int* __restrict__ nrows_ptr, int cap,
                  const unsigned short* __restrict__ h_hi,
                  const unsigned short* __restrict__ h_lo,
                  const unsigned short* __restrict__ w_hi,
                  const unsigned short* __restrict__ w_lo,
                  float* __restrict__ vbuf)
{
    constexpr int WROWS = BM / 2;
    constexpr int FM = WROWS / 16;
    constexpr int NRS = BM / 64;
    constexpr int SA = BM * 32;
    constexpr int SB = 128 * 32;
    constexpr int BUF = 2 * SA + 2 * SB;

    int nrows = nrows_ptr ? *nrows_ptr : nrows_lit;
    const int row0 = blockIdx.x * BM;
    if (row0 >= nrows) return;
    const int col0 = blockIdx.y * 128;
    const int kbeg = blockIdx.z * KTOT;
    const int kend = kbeg + KTOT;
    float* vout = vbuf + (size_t)blockIdx.z * cap * D5;

    const int tid = threadIdx.x, lane = tid & 63, w = tid >> 6;
    const int wm = w >> 1, wn = w & 1;

    __shared__ __align__(16) unsigned short smem[2 * BUF];

    const int sz8 = ((lane & 3) ^ ((lane >> 3) & 3)) * 8;
    size_t offL[NRS], offR[NRS];
#pragma unroll
    for (int rs = 0; rs < NRS; ++rs) {
        int rr = row0 + (w + 4 * rs) * 16 + (lane >> 2);
        if (rr > nrows - 1) rr = nrows - 1;
        int4 e = rowlist[rr];
        if (e.x < 0) { e.x = 0; e.y = 0; e.z = 1; }
        offL[rs] = ((size_t)(e.x * LM + e.y)) * D2;
        offR[rs] = ((size_t)(e.x * LM + e.z)) * D2;
    }
    size_t colOff[2];
#pragma unroll
    for (int cs = 0; cs < 2; ++cs)
        colOff[cs] = ((size_t)(col0 + (w + 4 * cs) * 16 + (lane >> 2))) * H4;

    auto stage = [&](int d, int k) {
        unsigned short* sb = smem + d * BUF;
#pragma unroll
        for (int j = 0; j < 2 * NRS; ++j) {
            const int pl = j / NRS, rs = j % NRS;
            const int g2 = w + 4 * rs;
            const unsigned short* hb = pl ? h_lo : h_hi;
            size_t off = (k < D2) ? (offL[rs] + k) : (offR[rs] + (k - D2));
            gload16(hb + off + sz8, sb + pl * SA + g2 * 512);
        }
#pragma unroll
        for (int j = 0; j < 4; ++j) {
            const int pl = j >> 1, cs = j & 1;
            const int g2 = w + 4 * cs;
            const unsigned short* wb = pl ? w_lo : w_hi;
            gload16(wb + colOff[cs] + k + sz8, sb + 2 * SA + pl * SB + g2 * 512);
        }
    };

    f32x4 acc[FM][4];
#pragma unroll
    for (int i = 0; i < FM; ++i)
#pragma unroll
        for (int j = 0; j < 4; ++j) acc[i][j] = (f32x4){0.f, 0.f, 0.f, 0.f};

    const int rsw = ((lane >> 4) ^ ((lane >> 1) & 3)) * 8;
    const int a_off = (wm * WROWS + (lane & 15)) * 32 + rsw;
    const int b_off = 2 * SA + (wn * 64 + (lane & 15)) * 32 + rsw;

    stage(0, kbeg);
    __syncthreads();
    int cur = 0;
    for (int k0 = kbeg; k0 < kend; k0 += 32) {
        if (k0 + 32 < kend) stage(cur ^ 1, k0 + 32);
        const unsigned short* sb = smem + cur * BUF;
        bf16x8 ah[FM], al[FM];
#pragma unroll
        for (int fm = 0; fm < FM; ++fm) {
            ah[fm] = *(const bf16x8*)&sb[a_off + fm * 512];
            al[fm] = *(const bf16x8*)&sb[SA + a_off + fm * 512];
        }
#pragma unroll
        for (int fn = 0; fn < 4; ++fn) {
            bf16x8 bh = *(const bf16x8*)&sb[b_off + fn * 512];
            bf16x8 bl = *(const bf16x8*)&sb[SB + b_off + fn * 512];
#pragma unroll
            for (int fm = 0; fm < FM; ++fm) {
                acc[fm][fn] = __builtin_amdgcn_mfma_f32_16x16x32_bf16(ah[fm], bh, acc[fm][fn], 0, 0, 0);
                acc[fm][fn] = __builtin_amdgcn_mfma_f32_16x16x32_bf16(ah[fm], bl, acc[fm][fn], 0, 0, 0);
                acc[fm][fn] = __builtin_amdgcn_mfma_f32_16x16x32_bf16(al[fm], bh, acc[fm][fn], 0, 0, 0);
            }
        }
        __syncthreads();
        cur ^= 1;
    }

#pragma unroll
    for (int fm = 0; fm < FM; ++fm) {
        int rbase = row0 + wm * WROWS + fm * 16 + (lane >> 4) * 4;
#pragma unroll
        for (int fn = 0; fn < 4; ++fn) {
            int c = col0 + wn * 64 + fn * 16 + (lane & 15);
#pragma unroll
            for (int q = 0; q < 4; ++q) {
                int r2 = rbase + q;
                if (r2 < nrows) vout[(size_t)r2 * D5 + c] = acc[fm][fn][q];
            }
        }
    }
}

// ---------------------------------------------------------------------------
// W-ONCE incremental pair GEMM: grid (40 coltiles, 4 kz); ONE block per W
// slice; BM=512 rows in-block (no re-read of W anywhere -> W fetched from
// HBM/L3 exactly once regardless of XCD placement). 512 thr = 8 waves (4x2),
// FM=8. LDS 160 KB: dbuf x (A 512x32 x2pl + B 128x32 x2pl).
// ---------------------------------------------------------------------------
template<int KTOT>
__global__ __launch_bounds__(512)
void gemm_pairs_big(const int4* __restrict__ rowlist,
                    const int* __restrict__ nrows_ptr, int cap,
                    const unsigned short* __restrict__ h_hi,
                    const unsigned short* __restrict__ h_lo,
                    const unsigned short* __restrict__ w_hi,
                    const unsigned short* __restrict__ w_lo,
                    float* __restrict__ vbuf)
{
    constexpr int SA = 512 * 32;     // shorts per A plane (16384)
    constexpr int SB = 128 * 32;     // shorts per B plane (4096)
    constexpr int BUF = 2 * SA + 2 * SB;   // 40960 shorts = 80 KB

    int nrows = *nrows_ptr;
    if (nrows <= 0) return;
    const int col0 = blockIdx.x * 128;
    const int kz = blockIdx.y;
    const int kbeg = kz * KTOT, kend = kbeg + KTOT;
    float* vout = vbuf + (size_t)kz * cap * D5;

    const int tid = threadIdx.x, lane = tid & 63, w = tid >> 6;   // w in 0..7
    const int wm = w >> 1, wn = w & 1;                             // 4 x 2 waves

    __shared__ __align__(16) unsigned short smem[2 * BUF];         // 160 KB

    const int sz8 = ((lane & 3) ^ ((lane >> 3) & 3)) * 8;  // swizzled source part
    // A sources: 4 row-groups per wave (i4*128 + w*16 + lane>>2)
    size_t offL[4], offR[4];
#pragma unroll
    for (int i4 = 0; i4 < 4; ++i4) {
        int rr = i4 * 128 + w * 16 + (lane >> 2);
        if (rr > nrows - 1) rr = nrows - 1;
        int4 e = rowlist[rr];
        if (e.x < 0) { e.x = 0; e.y = 0; e.z = 1; }
        offL[i4] = ((size_t)(e.x * LM + e.y)) * D2;
        offR[i4] = ((size_t)(e.x * LM + e.z)) * D2;
    }
    // B source: col = col0 + w*16 + lane>>2 (8 waves x 16 = 128 cols)
    const size_t colOff = ((size_t)(col0 + w * 16 + (lane >> 2))) * H4;

    auto stage = [&](int d, int k) {
        unsigned short* sb = smem + d * BUF;
#pragma unroll
        for (int pl = 0; pl < 2; ++pl) {
            const unsigned short* hb = pl ? h_lo : h_hi;
#pragma unroll
            for (int i4 = 0; i4 < 4; ++i4) {
                size_t off = (k < D2) ? (offL[i4] + k) : (offR[i4] + (k - D2));
                gload16(hb + off + sz8, sb + pl * SA + (i4 * 128 + w * 16) * 32);
            }
            const unsigned short* wb = pl ? w_lo : w_hi;
            gload16(wb + colOff + k + sz8, sb + 2 * SA + pl * SB + (w * 16) * 32);
        }
    };

    f32x4 acc[8][4];
#pragma unroll
    for (int i = 0; i < 8; ++i)
#pragma unroll
        for (int j = 0; j < 4; ++j) acc[i][j] = (f32x4){0.f, 0.f, 0.f, 0.f};

    const int rsw = ((lane >> 4) ^ ((lane >> 1) & 3)) * 8;   // swizzled read slot
    const int a_off = (wm * 128 + (lane & 15)) * 32 + rsw;   // + fm*16*32
    const int b_off = 2 * SA + (wn * 64 + (lane & 15)) * 32 + rsw;

    stage(0, kbeg);
    __syncthreads();
    int cur = 0;
    for (int k0 = kbeg; k0 < kend; k0 += 32) {
        if (k0 + 32 < kend) stage(cur ^ 1, k0 + 32);
        const unsigned short* sb = smem + cur * BUF;
        bf16x8 ah[8], al[8];
#pragma unroll
        for (int fm = 0; fm < 8; ++fm) {
            ah[fm] = *(const bf16x8*)&sb[a_off + fm * 512];
            al[fm] = *(const bf16x8*)&sb[SA + a_off + fm * 512];
        }
#pragma unroll
        for (int fn = 0; fn < 4; ++fn) {
            bf16x8 bh = *(const bf16x8*)&sb[b_off + fn * 512];
            bf16x8 bl = *(const bf16x8*)&sb[SB + b_off + fn * 512];
#pragma unroll
            for (int fm = 0; fm < 8; ++fm) {
                acc[fm][fn] = __builtin_amdgcn_mfma_f32_16x16x32_bf16(ah[fm], bh, acc[fm][fn], 0, 0, 0);
                acc[fm][fn] = __builtin_amdgcn_mfma_f32_16x16x32_bf16(ah[fm], bl, acc[fm][fn], 0, 0, 0);
                acc[fm][fn] = __builtin_amdgcn_mfma_f32_16x16x32_bf16(al[fm], bh, acc[fm][fn], 0, 0, 0);
            }
        }
        __syncthreads();
        cur ^= 1;
    }

#pragma unroll
    for (int fm = 0; fm < 8; ++fm) {
        int rbase = wm * 128 + fm * 16 + (lane >> 4) * 4;
#pragma unroll
        for (int fn = 0; fn < 4; ++fn) {
            int c = col0 + wn * 64 + fn * 16 + (lane & 15);
#pragma unroll
            for (int q = 0; q < 4; ++q) {
                int r2 = rbase + q;
                if (r2 < nrows) vout[(size_t)r2 * D5 + c] = acc[fm][fn][q];
            }
        }
    }
}

// ---------------------------------------------------------------------------
// Gates for one rowlist entry (all 256 threads). Sums nz split-K partials.
// ---------------------------------------------------------------------------
__device__ __forceinline__ void gates_row(int row, int4 e,
    const float* __restrict__ v_buf, int cap, int nz,
    const float* __restrict__ b_comp, const float* __restrict__ c_seq,
    const float* __restrict__ w_q,
    float* __restrict__ nh_cand, float* __restrict__ nc_cand,
    float* __restrict__ logits)
{
    int b = e.x, sL = e.y, sR = e.z;
    int cslot = e.w & 0xffff, plog = e.w >> 16;
    const float* v = v_buf + (size_t)row * D5;
    const size_t zstride = (size_t)cap * D5;
    const float* cl = c_seq + ((size_t)(b * LM + sL)) * D2;
    const float* cr = c_seq + ((size_t)(b * LM + sR)) * D2;
    float* nh = nh_cand + ((size_t)(b * 15 + cslot)) * D2;
    float* nc = nc_cand + ((size_t)(b * 15 + cslot)) * D2;

    float part = 0.f;
    for (int d = threadIdx.x; d < D2; d += 256) {
        float gi  = v[d];
        float gfl = v[D2 + d];
        float gfr = v[2 * D2 + d];
        float gu  = v[3 * D2 + d];
        float go  = v[4 * D2 + d];
        for (int z = 1; z < nz; ++z) {
            const float* vz = v + z * zstride;
            gi += vz[d]; gfl += vz[D2 + d]; gfr += vz[2 * D2 + d];
            gu += vz[3 * D2 + d]; go += vz[4 * D2 + d];
        }
        gi += b_comp[d]; gfl += b_comp[D2 + d]; gfr += b_comp[2 * D2 + d];
        gu += b_comp[3 * D2 + d]; go += b_comp[4 * D2 + d];
        float c = cl[d] * sigm(gfl + 1.0f) + cr[d] * sigm(gfr + 1.0f) + tanhf(gu) * sigm(gi);
        float h = sigm(go) * tanhf(c);
        nc[d] = c; nh[d] = h;
        part += h * w_q[d];
    }
    for (int o = 32; o > 0; o >>= 1) part += __shfl_down(part, o);
    __shared__ float wsum[4];
    if ((threadIdx.x & 63) == 0) wsum[threadIdx.x >> 6] = part;
    __syncthreads();
    if (threadIdx.x == 0) logits[b * 16 + plog] = wsum[0] + wsum[1] + wsum[2] + wsum[3];
    __syncthreads();
}

// ---------------------------------------------------------------------------
__global__ __launch_bounds__(256)
void gates_logits(const int4* __restrict__ rowlist, int nrows_lit,
                  const int* __restrict__ nrows_ptr,
                  const float* __restrict__ v_buf, int cap, int nz,
                  const float* __restrict__ b_comp,
                  const float* __restrict__ c_seq, const float* __restrict__ w_q,
                  float* __restrict__ nh, float* __restrict__ nc,
                  float* __restrict__ logits)
{
    int nrows = nrows_ptr ? *nrows_ptr : nrows_lit;
    int row = blockIdx.x;
    if (row >= nrows) return;
    int4 e = rowlist[row];
    if (e.x < 0) return;
    gates_row(row, e, v_buf, cap, nz, b_comp, c_seq, w_q, nh, nc, logits);
}

// ---------------------------------------------------------------------------
// Merge body for batch b (all 256 threads). Records per-batch slots
// (slotR: compacted row idx or -1; slotE: the rowlist entry).
// ---------------------------------------------------------------------------
__device__ void merge_body(int iter, int b, const int* __restrict__ lengths,
                  float* __restrict__ c_seq,
                  const float* __restrict__ nh_cand, const float* __restrict__ nc_cand,
                  float* __restrict__ logits, int* __restrict__ pos_idx,
                  int* __restrict__ pair_idx, int4* __restrict__ rowlist_out,
                  int* __restrict__ rcount, int4* __restrict__ slotE,
                  int* __restrict__ slotR,
                  unsigned short* __restrict__ h_hi, unsigned short* __restrict__ h_lo)
{
    int tid = threadIdx.x;
    int M = 15 - iter;
    int len = lengths[b];
    bool act = (iter + 1) < len;

    __shared__ float sl[16];
    __shared__ int sp[16], sq[16];
    __shared__ int s_sel;

    if (tid <= M) sp[tid] = pos_idx[b * 16 + tid];
    if (tid < M) { sq[tid] = pair_idx[b * 16 + tid]; sl[tid] = logits[b * 16 + tid]; }
    __syncthreads();

    if (tid == 0) {
        int sel = -1;
        if (act) {
            float best = -INFINITY; sel = 0;
            for (int p2 = 0; p2 < M; ++p2) {
                float mv = ((iter + 1 + p2) < len) ? sl[p2] : (sl[p2] - 10000.0f);
                if (mv > best) { best = mv; sel = p2; }
            }
        }
        s_sel = sel;
    }
    __syncthreads();
    int sel = s_sel;

    if (sel >= 0) {
        int slotL = sp[sel];
        int cslot = sq[sel];
        const float* nh = nh_cand + ((size_t)(b * 15 + cslot)) * D2;
        const float* nc = nc_cand + ((size_t)(b * 15 + cslot)) * D2;
        float* cd = c_seq + ((size_t)(b * LM + slotL)) * D2;
        unsigned short* hh = h_hi + ((size_t)(b * LM + slotL)) * D2;
        unsigned short* hl = h_lo + ((size_t)(b * LM + slotL)) * D2;
        for (int d = tid; d < D2; d += 256) {
            float hv = nh[d];
            cd[d] = nc[d];
            unsigned short hb = bf16_rne(hv);
            hh[d] = hb;
            hl[d] = bf16_rne(hv - bf16_tof(hb));
        }

        if (tid == 0) {
            for (int p2 = sel + 1; p2 < M; ++p2) sp[p2] = sp[p2 + 1];
            for (int p2 = sel + 1; p2 < M - 1; ++p2) { sq[p2] = sq[p2 + 1]; sl[p2] = sl[p2 + 1]; }
            int Mn = M - 1;
            if (iter < 14) {
                int s0 = -1, s1 = -1;
                if (sel - 1 >= 0) {
                    int4 e0 = make_int4(b, sp[sel - 1], sp[sel], sq[sel - 1] | ((sel - 1) << 16));
                    s0 = atomicAdd(rcount, 1);
                    rowlist_out[s0] = e0;
                    slotE[2 * b] = e0;
                }
                if (sel <= Mn - 1) {
                    int4 e1 = make_int4(b, sp[sel], sp[sel + 1], sq[sel] | (sel << 16));
                    s1 = atomicAdd(rcount, 1);
                    rowlist_out[s1] = e1;
                    slotE[2 * b + 1] = e1;
                }
                slotR[2 * b] = s0; slotR[2 * b + 1] = s1;
            }
            for (int p2 = 0; p2 < M; ++p2) pos_idx[b * 16 + p2] = sp[p2];
            for (int p2 = 0; p2 < Mn; ++p2) { pair_idx[b * 16 + p2] = sq[p2]; logits[b * 16 + p2] = sl[p2]; }
        }
    } else {
        if (tid == 0 && iter < 14) { slotR[2 * b] = -1; slotR[2 * b + 1] = -1; }
    }
}

__global__ __launch_bounds__(256)
void merge_kernel(int iter, const int* __restrict__ lens, float* __restrict__ c_seq,
                  const float* __restrict__ nh, const float* __restrict__ nc,
                  float* __restrict__ logits, int* __restrict__ pos, int* __restrict__ pair,
                  int4* __restrict__ rowlist_out, int* __restrict__ rcount,
                  int4* __restrict__ slotE, int* __restrict__ slotR,
                  unsigned short* __restrict__ h_hi, unsigned short* __restrict__ h_lo)
{
    merge_body(iter, blockIdx.x, lens, c_seq, nh, nc, logits, pos, pair,
               rowlist_out, rcount, slotE, slotR, h_hi, h_lo);
}

// ---------------------------------------------------------------------------
// Fused gates(it) + merge(it+1): the two candidate rows are processed
// CONCURRENTLY by half-blocks (128 threads each), then the merge runs with
// the full block. No cross-block dependency inside the kernel.
// ---------------------------------------------------------------------------
__global__ __launch_bounds__(256)
void gates_merge(int it, const int* __restrict__ lens,
                 const float* __restrict__ vbuf, int cap, int nz,
                 const float* __restrict__ b_comp, float* __restrict__ c_seq,
                 const float* __restrict__ w_q,
                 float* __restrict__ nh_cand, float* __restrict__ nc_cand,
                 float* __restrict__ logits,
                 int* __restrict__ pos, int* __restrict__ pair,
                 int4* __restrict__ rowlist_out, int* __restrict__ rc_next,
                 int4* __restrict__ slotE, int* __restrict__ slotR,
                 unsigned short* __restrict__ h_hi, unsigned short* __restrict__ h_lo)
{
    int b = blockIdx.x;
    int tid = threadIdx.x;
    int slot = tid >> 7, tid2 = tid & 127;
    int row = slotR[2 * b + slot];
    int4 e = slotE[2 * b + slot];

    __shared__ float wsum2[2][2];

    float part = 0.f;
    if (row >= 0) {
        int cslot = e.w & 0xffff;
        const float* v = vbuf + (size_t)row * D5;
        const size_t zstride = (size_t)cap * D5;
        const float* cl = c_seq + ((size_t)(b * LM + e.y)) * D2;
        const float* cr = c_seq + ((size_t)(b * LM + e.z)) * D2;
        float* nh = nh_cand + ((size_t)(b * 15 + cslot)) * D2;
        float* nc = nc_cand + ((size_t)(b * 15 + cslot)) * D2;
        for (int d = tid2; d < D2; d += 128) {
            float gi  = v[d];
            float gfl = v[D2 + d];
            float gfr = v[2 * D2 + d];
            float gu  = v[3 * D2 + d];
            float go  = v[4 * D2 + d];
            for (int z = 1; z < nz; ++z) {
                const float* vz = v + z * zstride;
                gi += vz[d]; gfl += vz[D2 + d]; gfr += vz[2 * D2 + d];
                gu += vz[3 * D2 + d]; go += vz[4 * D2 + d];
            }
            gi += b_comp[d]; gfl += b_comp[D2 + d]; gfr += b_comp[2 * D2 + d];
            gu += b_comp[3 * D2 + d]; go += b_comp[4 * D2 + d];
            float c = cl[d] * sigm(gfl + 1.0f) + cr[d] * sigm(gfr + 1.0f) + tanhf(gu) * sigm(gi);
            float h = sigm(go) * tanhf(c);
            nc[d] = c; nh[d] = h;
            part += h * w_q[d];
        }
    }
    for (int o = 32; o > 0; o >>= 1) part += __shfl_down(part, o);
    if ((tid2 & 63) == 0) wsum2[slot][tid2 >> 6] = part;
    __syncthreads();
    if (row >= 0 && tid2 == 0) {
        int plog = e.w >> 16;
        logits[b * 16 + plog] = wsum2[slot][0] + wsum2[slot][1];
    }
    __syncthreads();

    merge_body(it + 1, b, lens, c_seq, nh_cand, nc_cand, logits, pos, pair,
               rowlist_out, rc_next, slotE, slotR, h_hi, h_lo);
}

__global__ __launch_bounds__(256)
void copy_out(const unsigned short* __restrict__ h_hi,
              const unsigned short* __restrict__ h_lo, float* __restrict__ out)
{
    int b = blockIdx.x;
    size_t base = (size_t)(b * LM) * D2;
    for (int d = threadIdx.x; d < D2; d += 256)
        out[(size_t)b * D2 + d] = bf16_tof(h_hi[base + d]) + bf16_tof(h_lo[base + d]);
}

// ---------------------------------------------------------------------------
extern "C" void kernel_launch(void* const* d_in, const int* in_sizes, int n_in,
                              void* d_out, int out_size, void* d_ws, size_t ws_size,
                              hipStream_t stream)
{
    const float* x      = (const float*)d_in[0];
    const int*   lens   = (const int*)  d_in[1];
    const float* w_ih_f = (const float*)d_in[2];
    const float* w_hh_f = (const float*)d_in[3];
    const float* b_f    = (const float*)d_in[4];
    const float* w_ih_b = (const float*)d_in[5];
    const float* w_hh_b = (const float*)d_in[6];
    const float* b_b    = (const float*)d_in[7];
    const float* w_comp = (const float*)d_in[8];
    const float* b_comp = (const float*)d_in[9];
    const float* w_q    = (const float*)d_in[10];
    float* out = (float*)d_out;

    char* p = (char*)d_ws;
    auto alloc = [&](size_t bytes) {
        char* q = p; p += (bytes + 255) & ~(size_t)255; return q;
    };
    float* c_seq = (float*)alloc((size_t)NB * LM * D2 * 4);
    float* nh    = (float*)alloc((size_t)NB * 15 * D2 * 4);
    float* nc    = (float*)alloc((size_t)NB * 15 * D2 * 4);
    unsigned short* h_hi = (unsigned short*)alloc((size_t)NB * LM * D2 * 2);
    unsigned short* h_lo = (unsigned short*)alloc((size_t)NB * LM * D2 * 2);
    unsigned short* w_hi = (unsigned short*)alloc((size_t)D5 * H4 * 2);
    unsigned short* w_lo = (unsigned short*)alloc((size_t)D5 * H4 * 2);
    unsigned short* x_hi = (unsigned short*)alloc((size_t)NB * LM * HID * 2);
    unsigned short* x_lo = (unsigned short*)alloc((size_t)NB * LM * HID * 2);
    unsigned short* wl_hi = (unsigned short*)alloc((size_t)2 * H4 * 1024 * 2);
    unsigned short* wl_lo = (unsigned short*)alloc((size_t)2 * H4 * 1024 * 2);
    unsigned short* hc_hi = (unsigned short*)alloc((size_t)2 * NB * HID * 2);
    unsigned short* hc_lo = (unsigned short*)alloc((size_t)2 * NB * HID * 2);
    float* ccur  = (float*)alloc((size_t)2 * NB * HID * 4);
    float* logits = (float*)alloc((size_t)NB * 16 * 4);
    int*   pos    = (int*)alloc((size_t)NB * 16 * 4);
    int*   pair   = (int*)alloc((size_t)NB * 16 * 4);
    int4*  rowlist0   = (int4*)alloc((size_t)NPAIR0 * 16);
    int4*  rowlist_c  = (int4*)alloc((size_t)NPAIR0 * 16);
    int4*  rowlist_inc= (int4*)alloc((size_t)INC_CAP * 16);
    int4*  slotE  = (int4*)alloc((size_t)2 * NB * 16);
    int*   slotR  = (int*)alloc((size_t)2 * NB * 4);
    int*   rcount = (int*)alloc(16 * 4);
    // tail: gbuf (LSTM partials, 8.4MB) then reused as vbuf (pairs)
    char* tail = p;
    float* gbuf = (float*)tail;
    float* vbuf = (float*)tail;

    size_t used = (size_t)(tail - (char*)d_ws);
    size_t avail = (ws_size > used) ? (ws_size - used) : 0;
    size_t maxc = avail / ((size_t)D5 * 4);
    if (maxc > (size_t)NPAIR0) maxc = NPAIR0;
    int chunk = ((int)maxc) & ~127;
    if (chunk < 2048) chunk = 2048;   // need >= 4*INC_CAP rows of vbuf anyway

    hipMemsetAsync(rcount, 0, 64, stream);
    init_kernel<<<dim3(NB), dim3(256), 0, stream>>>(lens, ccur, hc_hi, hc_lo, pos, pair,
                                                    rowlist0, rowlist_c, rcount, logits);
    split_w<<<dim3(2048), dim3(256), 0, stream>>>((const float4*)w_comp, w_hi, w_lo, (int)((size_t)D5 * H4 / 4));
    split_w<<<dim3(1024), dim3(256), 0, stream>>>((const float4*)x, x_hi, x_lo, (int)((size_t)NB * LM * HID / 4));
    pack_lstm_w<<<dim3(1024), dim3(256), 0, stream>>>(w_ih_f, w_hh_f, w_ih_b, w_hh_b, wl_hi, wl_lo);

    // ---- bidirectional LSTM, 16 sequential steps (split-K x2, grouped) ----
    for (int t = 0; t < 16; ++t) {
        gemm_lstm_g<<<dim3(256), dim3(256), 0, stream>>>(
            t, lens, x_hi, x_lo, hc_hi, hc_lo, wl_hi, wl_lo, gbuf);
        lstm_gate<<<dim3(NB, 2), dim3(256), 0, stream>>>(
            t, lens, b_f, b_b, gbuf, ccur, hc_hi, hc_lo, h_hi, h_lo, c_seq);
    }

    // ---- iter 0: candidates + logits (length-compacted if vbuf fits) ----
    if (chunk >= NPAIR0) {
        gemm_pairs_g<128, 2048><<<dim3(30, 40, 1), dim3(256), 0, stream>>>(
            rowlist_c, NPAIR0, (const int*)(rcount + 15), 0,
            h_hi, h_lo, w_hi, w_lo, vbuf);
        gates_logits<<<dim3(NPAIR0), dim3(256), 0, stream>>>(
            rowlist_c, NPAIR0, (const int*)(rcount + 15),
            vbuf, 0, 1, b_comp, c_seq, w_q, nh, nc, logits);
    } else {
        for (int off = 0; off < NPAIR0; off += chunk) {
            int rows = NPAIR0 - off; if (rows > chunk) rows = chunk;
            int RT = (rows + 127) >> 7;
            gemm_pairs_g<128, 2048><<<dim3(RT, 40, 1), dim3(256), 0, stream>>>(
                rowlist0 + off, rows, (const int*)nullptr, 0,
                h_hi, h_lo, w_hi, w_lo, vbuf);
            gates_logits<<<dim3(rows), dim3(256), 0, stream>>>(
                rowlist0 + off, rows, (const int*)nullptr,
                vbuf, 0, 1, b_comp, c_seq, w_q, nh, nc, logits);
        }
    }

    // ---- merge(0), then 14 iterations of { W-once gemm ; gates+merge } ----
    merge_kernel<<<dim3(NB), dim3(256), 0, stream>>>(
        0, lens, c_seq, nh, nc, logits, pos, pair,
        rowlist_inc, rcount + 0, slotE, slotR, h_hi, h_lo);
    for (int it = 0; it < 14; ++it) {
        gemm_pairs_big<512><<<dim3(40, 4), dim3(512), 0, stream>>>(
            rowlist_inc, (const int*)(rcount + it), INC_CAP,
            h_hi, h_lo, w_hi, w_lo, vbuf);
        gates_merge<<<dim3(NB), dim3(256), 0, stream>>>(
            it, lens, vbuf, INC_CAP, 4, b_comp, c_seq, w_q, nh, nc, logits,
            pos, pair, rowlist_inc, rcount + it + 1, slotE, slotR, h_hi, h_lo);
    }

    copy_out<<<dim3(NB), dim3(256), 0, stream>>>(h_hi, h_lo, out);
}